// Round 1
// baseline (10203.704 us; speedup 1.0000x reference)
//
#include <hip/hip_runtime.h>
#include <cstddef>

// LSTM: N=64 batch, T=512 steps, D=512 in, H=512 hidden.
// gates[t] = [x_t | h_{t-1}] @ [Wx; Wh] + b  (K=1024, fp16 MFMA, fp32 accum)
// Persistent scan kernel: 128 WGs x 256 thr, each WG owns 16 gate columns
// (4 hidden units x 4 gates), weight slices resident in LDS, custom
// device-scope barrier between timesteps.

typedef _Float16 half8 __attribute__((ext_vector_type(8)));
typedef float f32x4 __attribute__((ext_vector_type(4)));

#define NBATCH 64
#define TSTEPS 512
#define DIN    512
#define HID    512
#define NCOL   2048
#define SCAN_WGS 128
#define LDK    520   // padded k-stride for LDS weight slices (16B-aligned rows)

__device__ __forceinline__ float fast_sigmoid(float x) {
  return 1.0f / (1.0f + __expf(-x));
}
__device__ __forceinline__ float fast_tanh(float x) {
  // graceful saturation at +/-inf
  return 1.0f - 2.0f / (__expf(2.0f * x) + 1.0f);
}

// one-time per launch: x -> fp16, h0 -> h ping buffer, reset barrier counter
__global__ void lstm_prep(const float* __restrict__ x, const float* __restrict__ h0,
                          _Float16* __restrict__ xb, _Float16* __restrict__ hbuf,
                          unsigned* __restrict__ ctr)
{
  size_t gid = (size_t)blockIdx.x * blockDim.x + threadIdx.x;
  size_t stride = (size_t)gridDim.x * blockDim.x;
  const size_t NX = (size_t)NBATCH * TSTEPS * DIN;
  for (size_t i = gid * 4; i < NX; i += stride * 4) {
    float4 v = *(const float4*)(x + i);
    xb[i + 0] = (_Float16)v.x;
    xb[i + 1] = (_Float16)v.y;
    xb[i + 2] = (_Float16)v.z;
    xb[i + 3] = (_Float16)v.w;
  }
  for (size_t i = gid; i < (size_t)NBATCH * HID; i += stride)
    hbuf[i] = (_Float16)h0[i];
  if (gid == 0) *ctr = 0u;
}

__global__ __launch_bounds__(256, 1) void lstm_scan(
    const _Float16* __restrict__ xb,   // [N*T][D] fp16
    const float* __restrict__ Wx,      // [D][4H]
    const float* __restrict__ Wh,      // [H][4H]
    const float* __restrict__ bias,    // [4H]
    _Float16* __restrict__ hbuf,       // [2][N][H] fp16 ping-pong
    float* __restrict__ out,           // [N][T][H] fp32
    unsigned* __restrict__ ctr)        // barrier counter
{
  __shared__ _Float16 WxT[16][LDK];    // [col][k], fp16, 16.6 KB
  __shared__ _Float16 WhT[16][LDK];    // 16.6 KB
  __shared__ float gl[NBATCH][17];     // gates staging, 4.4 KB
  __shared__ float cl[NBATCH][4];      // cell state (persistent), 1 KB
  __shared__ float bl[16];             // bias slice

  const int wg   = blockIdx.x;         // 0..127: owns hidden units wg*4..wg*4+3
  const int tid  = threadIdx.x;
  const int lane = tid & 63;
  const int wave = tid >> 6;           // 0..3: m-tile (16 batch rows each)

  // ---- one-time: stage weight slices fp32->fp16 into LDS ----
  {
    const int gate = tid & 3;
    const int k0   = tid >> 2;         // 0..63
    for (int pass = 0; pass < 8; ++pass) {
      int k = k0 + pass * 64;
      float4 vx = *(const float4*)(Wx + (size_t)k * NCOL + gate * 512 + wg * 4);
      float4 vh = *(const float4*)(Wh + (size_t)k * NCOL + gate * 512 + wg * 4);
      WxT[gate * 4 + 0][k] = (_Float16)vx.x;
      WxT[gate * 4 + 1][k] = (_Float16)vx.y;
      WxT[gate * 4 + 2][k] = (_Float16)vx.z;
      WxT[gate * 4 + 3][k] = (_Float16)vx.w;
      WhT[gate * 4 + 0][k] = (_Float16)vh.x;
      WhT[gate * 4 + 1][k] = (_Float16)vh.y;
      WhT[gate * 4 + 2][k] = (_Float16)vh.z;
      WhT[gate * 4 + 3][k] = (_Float16)vh.w;
    }
    if (tid < 16) bl[tid] = bias[(tid >> 2) * 512 + wg * 4 + (tid & 3)];
    for (int i = tid; i < NBATCH * 4; i += 256) cl[i >> 2][i & 3] = 0.0f;
  }
  __syncthreads();

  // MFMA 16x16x32 fragment indices (A: row=lane&15, k=(lane>>4)*8+j;
  //  B: col=lane&15, k=(lane>>4)*8+j; D: col=lane&15, row=(lane>>4)*4+j)
  const int fr = lane & 15;
  const int fk = (lane >> 4) * 8;
  const int mrow = wave * 16 + fr;     // batch row this lane loads A for
  const int n_ep = tid >> 2;           // epilogue: cell (n, hj)
  const int hj_ep = tid & 3;
  const size_t out_col = (size_t)wg * 4 + hj_ep;

  // preload x fragments for t=0 (x never depends on the barrier)
  half8 xa[16];
#pragma unroll
  for (int ks = 0; ks < 16; ++ks)
    xa[ks] = *(const half8*)(xb + ((size_t)mrow * TSTEPS + 0) * DIN + ks * 32 + fk);

  for (int t = 0; t < TSTEPS; ++t) {
    if (t > 0) {
      if (tid == 0) {
        const unsigned tgt = (unsigned)(SCAN_WGS * t);
        while (__hip_atomic_load(ctr, __ATOMIC_RELAXED, __HIP_MEMORY_SCOPE_AGENT) < tgt)
          __builtin_amdgcn_s_sleep(1);
        __threadfence();               // acquire: invalidate stale h lines
      }
      __syncthreads();
    }

    // issue h-fragment loads first so they fly under the x-MFMA phase
    const _Float16* hsrc = hbuf + (size_t)(t & 1) * (NBATCH * HID) + (size_t)mrow * HID;
    half8 ha[16];
#pragma unroll
    for (int ks = 0; ks < 16; ++ks)
      ha[ks] = *(const half8*)(hsrc + ks * 32 + fk);

    f32x4 acc0 = {0.f, 0.f, 0.f, 0.f};
    f32x4 acc1 = {0.f, 0.f, 0.f, 0.f};
#pragma unroll
    for (int ks = 0; ks < 16; ks += 2) {
      half8 b0 = *(const half8*)(&WxT[fr][ks * 32 + fk]);
      half8 b1 = *(const half8*)(&WxT[fr][(ks + 1) * 32 + fk]);
      acc0 = __builtin_amdgcn_mfma_f32_16x16x32_f16(xa[ks],     b0, acc0, 0, 0, 0);
      acc1 = __builtin_amdgcn_mfma_f32_16x16x32_f16(xa[ks + 1], b1, acc1, 0, 0, 0);
    }
#pragma unroll
    for (int ks = 0; ks < 16; ks += 2) {
      half8 b0 = *(const half8*)(&WhT[fr][ks * 32 + fk]);
      half8 b1 = *(const half8*)(&WhT[fr][(ks + 1) * 32 + fk]);
      acc0 = __builtin_amdgcn_mfma_f32_16x16x32_f16(ha[ks],     b0, acc0, 0, 0, 0);
      acc1 = __builtin_amdgcn_mfma_f32_16x16x32_f16(ha[ks + 1], b1, acc1, 0, 0, 0);
    }
    f32x4 acc = acc0 + acc1;

    // stage gates to LDS (D layout: col=lane&15, row=(lane>>4)*4+j)
    {
      int gr = wave * 16 + ((lane >> 4) << 2);
#pragma unroll
      for (int j = 0; j < 4; ++j) gl[gr + j][fr] = acc[j];
    }
    __syncthreads();

    // epilogue: one (n, hidden-unit) cell per thread
    {
      float iv = gl[n_ep][0  + hj_ep] + bl[0  + hj_ep];
      float fv = gl[n_ep][4  + hj_ep] + bl[4  + hj_ep];
      float ov = gl[n_ep][8  + hj_ep] + bl[8  + hj_ep];
      float gv = gl[n_ep][12 + hj_ep] + bl[12 + hj_ep];
      float ig = fast_sigmoid(iv);
      float fg = fast_sigmoid(fv);
      float og = fast_sigmoid(ov);
      float gg = fast_tanh(gv);
      float c = fg * cl[n_ep][hj_ep] + ig * gg;
      cl[n_ep][hj_ep] = c;
      float h = og * fast_tanh(c);
      out[((size_t)n_ep * TSTEPS + t) * HID + out_col] = h;
      hbuf[(size_t)((t + 1) & 1) * (NBATCH * HID) + (size_t)n_ep * HID + out_col] =
          (_Float16)h;
    }

    __threadfence();                   // release h/out stores device-wide
    __syncthreads();                   // all threads of WG fenced
    if (tid == 0) atomicAdd(ctr, 1u);  // arrive

    // prefetch x fragments for t+1; overlaps the next barrier spin
    if (t + 1 < TSTEPS) {
#pragma unroll
      for (int ks = 0; ks < 16; ++ks)
        xa[ks] = *(const half8*)(xb + ((size_t)mrow * TSTEPS + (t + 1)) * DIN + ks * 32 + fk);
    }
  }
}

extern "C" void kernel_launch(void* const* d_in, const int* in_sizes, int n_in,
                              void* d_out, int out_size, void* d_ws, size_t ws_size,
                              hipStream_t stream) {
  const float* x  = (const float*)d_in[0];
  const float* h0 = (const float*)d_in[1];
  const float* Wx = (const float*)d_in[2];
  const float* Wh = (const float*)d_in[3];
  const float* b  = (const float*)d_in[4];
  float* out = (float*)d_out;

  char* ws = (char*)d_ws;
  _Float16* xb   = (_Float16*)ws;                            // 33,554,432 B
  _Float16* hbuf = (_Float16*)(ws + 33554432);               //    131,072 B
  unsigned* ctr  = (unsigned*)(ws + 33554432 + 131072);      //          4 B

  lstm_prep<<<dim3(2048), dim3(256), 0, stream>>>(x, h0, xb, hbuf, ctr);
  lstm_scan<<<dim3(SCAN_WGS), dim3(256), 0, stream>>>(xb, Wx, Wh, b, hbuf, out, ctr);
}

// Round 2
// 2719.528 us; speedup vs baseline: 3.7520x; 3.7520x over previous
//
#include <hip/hip_runtime.h>
#include <cstddef>

// LSTM: N=64, T=512, D=512, H=512.
// gates[t] = [x_t | h_{t-1}] @ [Wx; Wh] + b  (K=1024, fp16 MFMA, fp32 accum)
// Persistent scan: 128 WGs x 256 thr, each WG owns 4 hidden units (16 gate
// cols), weight slices in LDS. Fence-free cross-WG sync: h exchanged via
// agent-scope (sc1) IC-coherent loads/stores, per-WG monotonic flags,
// release = s_waitcnt vmcnt(0) + syncthreads (no L2 wbl2/inv).

typedef _Float16 half8 __attribute__((ext_vector_type(8)));
typedef float f32x4 __attribute__((ext_vector_type(4)));

#define NBATCH 64
#define TSTEPS 512
#define DIN    512
#define HID    512
#define NCOL   2048
#define SCAN_WGS 128
#define LDK    536   // padded k-stride (bytes 1072 -> bank-start spacing 12)

__device__ __forceinline__ float fast_sigmoid(float x) {
  return 1.0f / (1.0f + __expf(-x));
}
__device__ __forceinline__ float fast_tanh(float x) {
  return 1.0f - 2.0f / (__expf(2.0f * x) + 1.0f);
}

// one-time per launch: x -> fp16, h0 -> h ping buffer, reset flags
__global__ void lstm_prep(const float* __restrict__ x, const float* __restrict__ h0,
                          _Float16* __restrict__ xb, _Float16* __restrict__ hbuf,
                          unsigned* __restrict__ flags)
{
  size_t gid = (size_t)blockIdx.x * blockDim.x + threadIdx.x;
  size_t stride = (size_t)gridDim.x * blockDim.x;
  const size_t NX = (size_t)NBATCH * TSTEPS * DIN;
  for (size_t i = gid * 4; i < NX; i += stride * 4) {
    float4 v = *(const float4*)(x + i);
    xb[i + 0] = (_Float16)v.x;
    xb[i + 1] = (_Float16)v.y;
    xb[i + 2] = (_Float16)v.z;
    xb[i + 3] = (_Float16)v.w;
  }
  for (size_t i = gid; i < (size_t)NBATCH * HID; i += stride)
    hbuf[i] = (_Float16)h0[i];
  if (gid < SCAN_WGS) flags[gid] = 0u;
}

__global__ __launch_bounds__(256, 1) void lstm_scan(
    const _Float16* __restrict__ xb,   // [N*T][D] fp16
    const float* __restrict__ Wx,      // [D][4H]
    const float* __restrict__ Wh,      // [H][4H]
    const float* __restrict__ bias,    // [4H]
    _Float16* __restrict__ hbuf,       // [2][N][H] fp16 ping-pong
    float* __restrict__ out,           // [N][T][H] fp32
    unsigned* __restrict__ flags)      // [128] monotonic per-WG step counters
{
  __shared__ _Float16 WxT[16][LDK];    // [col][k]
  __shared__ _Float16 WhT[16][LDK];
  __shared__ float gl[NBATCH][17];     // gates staging
  __shared__ float cl[NBATCH][4];      // cell state (persistent)
  __shared__ float bl[16];             // bias slice

  const int wg   = blockIdx.x;         // owns hidden units wg*4..wg*4+3
  const int tid  = threadIdx.x;
  const int lane = tid & 63;
  const int wave = tid >> 6;           // m-tile (16 batch rows each)

  // ---- one-time: stage weight slices fp32->fp16 into LDS ----
  {
    const int gate = tid & 3;
    const int k0   = tid >> 2;         // 0..63
    for (int pass = 0; pass < 8; ++pass) {
      int k = k0 + pass * 64;
      float4 vx = *(const float4*)(Wx + (size_t)k * NCOL + gate * 512 + wg * 4);
      float4 vh = *(const float4*)(Wh + (size_t)k * NCOL + gate * 512 + wg * 4);
      WxT[gate * 4 + 0][k] = (_Float16)vx.x;
      WxT[gate * 4 + 1][k] = (_Float16)vx.y;
      WxT[gate * 4 + 2][k] = (_Float16)vx.z;
      WxT[gate * 4 + 3][k] = (_Float16)vx.w;
      WhT[gate * 4 + 0][k] = (_Float16)vh.x;
      WhT[gate * 4 + 1][k] = (_Float16)vh.y;
      WhT[gate * 4 + 2][k] = (_Float16)vh.z;
      WhT[gate * 4 + 3][k] = (_Float16)vh.w;
    }
    if (tid < 16) bl[tid] = bias[(tid >> 2) * 512 + wg * 4 + (tid & 3)];
    for (int i = tid; i < NBATCH * 4; i += 256) cl[i >> 2][i & 3] = 0.0f;
  }
  __syncthreads();

  // MFMA 16x16x32 fragment indices (A: row=lane&15, k=(lane>>4)*8+j;
  //  B: col=lane&15, k=(lane>>4)*8+j; D: col=lane&15, row=(lane>>4)*4+j)
  const int fr = lane & 15;
  const int fk = (lane >> 4) * 8;
  const int mrow = wave * 16 + fr;
  const int n_ep = tid >> 2;
  const int hj_ep = tid & 3;
  const size_t out_col = (size_t)wg * 4 + hj_ep;

  // preload x fragments for t=0
  half8 xa[16];
#pragma unroll
  for (int ks = 0; ks < 16; ++ks)
    xa[ks] = *(const half8*)(xb + ((size_t)mrow * TSTEPS + 0) * DIN + ks * 32 + fk);

  for (int t = 0; t < TSTEPS; ++t) {
    // ---- wait: all 128 WGs have published h-input for step t ----
    if (t > 0) {
      if (tid < 64) {
        const unsigned tgt = (unsigned)t;
        for (;;) {
          unsigned long long v = __hip_atomic_load(
              (const unsigned long long*)flags + tid,
              __ATOMIC_RELAXED, __HIP_MEMORY_SCOPE_AGENT);
          bool ok = ((unsigned)v >= tgt) && ((unsigned)(v >> 32) >= tgt);
          if (__all(ok)) break;
          __builtin_amdgcn_s_sleep(1);
        }
      }
      __syncthreads();
    }

    // ---- issue coherent h-fragment loads (complete under the x-MFMA phase)
    const _Float16* hsrc = hbuf + (size_t)(t & 1) * (NBATCH * HID) + (size_t)mrow * HID;
    half8 ha[16];
#pragma unroll
    for (int ks = 0; ks < 16; ++ks) {
      const _Float16* p = hsrc + ks * 32 + fk;
      asm volatile("global_load_dwordx4 %0, %1, off sc1"
                   : "=v"(ha[ks]) : "v"(p) : "memory");
    }

    f32x4 a0 = {0.f, 0.f, 0.f, 0.f};
    f32x4 a1 = {0.f, 0.f, 0.f, 0.f};
    f32x4 a2 = {0.f, 0.f, 0.f, 0.f};
    f32x4 a3 = {0.f, 0.f, 0.f, 0.f};
#pragma unroll
    for (int ks = 0; ks < 16; ks += 4) {
      half8 b0 = *(const half8*)(&WxT[fr][ks * 32 + fk]);
      half8 b1 = *(const half8*)(&WxT[fr][(ks + 1) * 32 + fk]);
      half8 b2 = *(const half8*)(&WxT[fr][(ks + 2) * 32 + fk]);
      half8 b3 = *(const half8*)(&WxT[fr][(ks + 3) * 32 + fk]);
      a0 = __builtin_amdgcn_mfma_f32_16x16x32_f16(xa[ks],     b0, a0, 0, 0, 0);
      a1 = __builtin_amdgcn_mfma_f32_16x16x32_f16(xa[ks + 1], b1, a1, 0, 0, 0);
      a2 = __builtin_amdgcn_mfma_f32_16x16x32_f16(xa[ks + 2], b2, a2, 0, 0, 0);
      a3 = __builtin_amdgcn_mfma_f32_16x16x32_f16(xa[ks + 3], b3, a3, 0, 0, 0);
    }

    // h loads must have landed before the h-MFMA phase (rule #18 fence)
    asm volatile("s_waitcnt vmcnt(0)" ::: "memory");
    __builtin_amdgcn_sched_barrier(0);

#pragma unroll
    for (int ks = 0; ks < 16; ks += 4) {
      half8 b0 = *(const half8*)(&WhT[fr][ks * 32 + fk]);
      half8 b1 = *(const half8*)(&WhT[fr][(ks + 1) * 32 + fk]);
      half8 b2 = *(const half8*)(&WhT[fr][(ks + 2) * 32 + fk]);
      half8 b3 = *(const half8*)(&WhT[fr][(ks + 3) * 32 + fk]);
      a0 = __builtin_amdgcn_mfma_f32_16x16x32_f16(ha[ks],     b0, a0, 0, 0, 0);
      a1 = __builtin_amdgcn_mfma_f32_16x16x32_f16(ha[ks + 1], b1, a1, 0, 0, 0);
      a2 = __builtin_amdgcn_mfma_f32_16x16x32_f16(ha[ks + 2], b2, a2, 0, 0, 0);
      a3 = __builtin_amdgcn_mfma_f32_16x16x32_f16(ha[ks + 3], b3, a3, 0, 0, 0);
    }
    f32x4 acc = (a0 + a1) + (a2 + a3);

    // stage gates to LDS (D layout: col=lane&15, row=(lane>>4)*4+j)
    {
      int gr = wave * 16 + ((lane >> 4) << 2);
#pragma unroll
      for (int j = 0; j < 4; ++j) gl[gr + j][fr] = acc[j];
    }
    __syncthreads();

    // ---- epilogue: one (n, hidden-unit) cell per thread ----
    {
      float iv = gl[n_ep][0  + hj_ep] + bl[0  + hj_ep];
      float fv = gl[n_ep][4  + hj_ep] + bl[4  + hj_ep];
      float ov = gl[n_ep][8  + hj_ep] + bl[8  + hj_ep];
      float gv = gl[n_ep][12 + hj_ep] + bl[12 + hj_ep];
      float ig = fast_sigmoid(iv);
      float fg = fast_sigmoid(fv);
      float og = fast_sigmoid(ov);
      float gg = fast_tanh(gv);
      float c = fg * cl[n_ep][hj_ep] + ig * gg;
      cl[n_ep][hj_ep] = c;
      float hval = og * fast_tanh(c);
      out[((size_t)n_ep * TSTEPS + t) * HID + out_col] = hval;

      // pack fp16 pair with partner lane (hj^1) and publish via IC-coherent
      // b32 atomic store (no L2 dirty state -> no release flush needed)
      float hpart = __shfl_xor(hval, 1);
      if ((hj_ep & 1) == 0) {
        _Float16 lo = (_Float16)hval, hi = (_Float16)hpart;
        unsigned packed = (unsigned)__builtin_bit_cast(unsigned short, lo) |
                          ((unsigned)__builtin_bit_cast(unsigned short, hi) << 16);
        unsigned* dst = (unsigned*)(hbuf + (size_t)((t + 1) & 1) * (NBATCH * HID) +
                                    (size_t)n_ep * HID + wg * 4 + hj_ep);
        __hip_atomic_store(dst, packed, __ATOMIC_RELAXED, __HIP_MEMORY_SCOPE_AGENT);
      }
    }

    // ---- release: drain this wave's h stores, then arrive ----
    asm volatile("s_waitcnt vmcnt(0)" ::: "memory");
    __syncthreads();                   // all waves' stores drained
    if (tid == 0)
      __hip_atomic_store(&flags[wg], (unsigned)(t + 1),
                         __ATOMIC_RELAXED, __HIP_MEMORY_SCOPE_AGENT);

    // prefetch x fragments for t+1; overlaps the next poll
    if (t + 1 < TSTEPS) {
#pragma unroll
      for (int ks = 0; ks < 16; ++ks)
        xa[ks] = *(const half8*)(xb + ((size_t)mrow * TSTEPS + (t + 1)) * DIN + ks * 32 + fk);
    }
  }
}

extern "C" void kernel_launch(void* const* d_in, const int* in_sizes, int n_in,
                              void* d_out, int out_size, void* d_ws, size_t ws_size,
                              hipStream_t stream) {
  const float* x  = (const float*)d_in[0];
  const float* h0 = (const float*)d_in[1];
  const float* Wx = (const float*)d_in[2];
  const float* Wh = (const float*)d_in[3];
  const float* b  = (const float*)d_in[4];
  float* out = (float*)d_out;

  char* ws = (char*)d_ws;
  _Float16* xb    = (_Float16*)ws;                           // 33,554,432 B
  _Float16* hbuf  = (_Float16*)(ws + 33554432);              //    131,072 B
  unsigned* flags = (unsigned*)(ws + 33554432 + 131072);     //        512 B

  lstm_prep<<<dim3(2048), dim3(256), 0, stream>>>(x, h0, xb, hbuf, flags);
  lstm_scan<<<dim3(SCAN_WGS), dim3(256), 0, stream>>>(xb, Wx, Wh, b, hbuf, out, flags);
}